// Round 10
// baseline (106.262 us; speedup 1.0000x reference)
//
#include <hip/hip_runtime.h>

// Conv2d 3x3, cin=4, cout=4, pad=1, stride=1 on [4,4096,4096] fp32.
//
// Round-10 = round-9 (2-phase global_load_lds pipeline, counted vmcnt(7))
// with the 8-way-conflicted L/R halo ds_read_b32 replaced by wave shuffles:
// lane i's left halo == lane i-1's a.w, right halo == lane i+1's a.x
// (ds_bpermute, conflict-free). Only wave-edge lanes (l==0 / l==63) read
// LDS/halo slots (1 active lane -> no conflict). LROW 1028 -> 1024 (pad no
// longer needed). Everything else identical to the 97.9 us round-9 kernel.

#define IW 4096
#define IH 4096
constexpr long long HWsz = (long long)IH * IW;

typedef float v4f __attribute__((ext_vector_type(4)));

#define LROW 1024   // interior floats only; halos live in hbuf

__device__ __forceinline__ void gload_lds16(const float* g, float* l) {
    __builtin_amdgcn_global_load_lds(
        (const __attribute__((address_space(1))) char*)g,
        (__attribute__((address_space(3))) char*)l, 16, 0, 0);
}
__device__ __forceinline__ void gload_lds4(const float* g, float* l) {
    __builtin_amdgcn_global_load_lds(
        (const __attribute__((address_space(1))) char*)g,
        (__attribute__((address_space(3))) char*)l, 4, 0, 0);
}

// issue 7 DMAs per wave: 6 interior row-chunks (width 16) + 1 halo (width 4)
__device__ __forceinline__ void stage(const float* __restrict__ xin, int ci,
                                      float (*rbuf)[LROW], float* hbuf,
                                      int y0, int X0, int w, int l) {
    const float* plane = xin + (long long)ci * HWsz;
    const int xg = X0 + 256 * w + 4 * l;          // per-lane global x
    #pragma unroll
    for (int r = 0; r < 6; ++r) {
        int yy = y0 - 1 + r;
        int yc = yy < 0 ? 0 : (yy >= IH ? IH - 1 : yy);   // clamp: pad rows
        gload_lds16(plane + (long long)yc * IW + xg, &rbuf[r][256 * w]);
    }
    if (l < 3) {                                   // 4 waves x 3 lanes = 12 slots
        const int s   = 3 * w + l;                 // slot = 2*r + side
        const int r   = s >> 1;
        const int sid = s & 1;
        int yy = y0 - 1 + r;
        int yc = yy < 0 ? 0 : (yy >= IH ? IH - 1 : yy);
        int x  = sid ? (X0 + 1024) : (X0 - 1);
        int xc = x < 0 ? 0 : (x >= IW ? IW - 1 : x);
        gload_lds4(plane + (long long)yc * IW + xc, &hbuf[3 * w]);
    }
}

__device__ __forceinline__ void compute_ci(float acc[4][4][4],
                                           const float (*rbuf)[LROW],
                                           const float* hbuf,
                                           const float* __restrict__ wt, int ci,
                                           int y0, int t, int l,
                                           bool xlo, bool xhi) {
    #pragma unroll
    for (int dy = 0; dy < 6; ++dy) {
        const int yy = y0 - 1 + dy;
        if (yy >= 0 && yy < IH) {                  // wave-uniform row skip
            const v4f a = *reinterpret_cast<const v4f*>(&rbuf[dy][4 * t]);
            // halos from neighbor lanes' registers (conflict-free bpermute)
            float L = __shfl_up(a.w, 1);
            float R = __shfl_down(a.x, 1);
            if (l == 0)                            // 1 active lane per wave
                L = (t == 0)   ? (xlo ? 0.f : hbuf[2 * dy])
                               : rbuf[dy][4 * t - 1];
            if (l == 63)
                R = (t == 255) ? (xhi ? 0.f : hbuf[2 * dy + 1])
                               : rbuf[dy][4 * t + 4];
            float vv[6] = {L, a.x, a.y, a.z, a.w, R};
            #pragma unroll
            for (int rk = 0; rk < 3; ++rk) {
                const int o = dy - rk;             // output row offset
                if (o >= 0 && o < 4) {
                    #pragma unroll
                    for (int co = 0; co < 4; ++co) {
                        #pragma unroll
                        for (int kx = 0; kx < 3; ++kx) {
                            const float w = wt[((co * 4 + ci) * 3 + rk) * 3 + kx];
                            #pragma unroll
                            for (int p = 0; p < 4; ++p)
                                acc[o][co][p] = fmaf(w, vv[p + kx], acc[o][co][p]);
                        }
                    }
                }
            }
        }
    }
}

__global__ __launch_bounds__(256) void conv3x3_kernel(
    const float* __restrict__ xin,   // [4][4096][4096]
    const float* __restrict__ wt,    // [4][4][3][3]
    float* __restrict__ out)         // [4][4096][4096]
{
    __shared__ __align__(16) float rows[2][6][LROW];   // 49152 B
    __shared__ float halo[2][12];

    // grid 4096 = 1024 row-blocks x 4 x-strips; bijective XCD swizzle
    const int bid = blockIdx.x;
    const int swz = (bid & 7) * 512 + (bid >> 3);
    const int rowblk = swz >> 2;
    const int xq     = swz & 3;
    const int y0     = rowblk << 2;               // 4 output rows
    const int X0     = xq << 10;                  // 1024-px strip
    const int t      = (int)threadIdx.x;
    const int w      = t >> 6, l = t & 63;
    const bool xlo   = (X0 == 0);
    const bool xhi   = (X0 + 1024 == IW);

    float acc[4][4][4];
    #pragma unroll
    for (int o = 0; o < 4; ++o)
        #pragma unroll
        for (int co = 0; co < 4; ++co)
            #pragma unroll
            for (int p = 0; p < 4; ++p) acc[o][co][p] = 0.f;

    stage(xin, 0, rows[0], halo[0], y0, X0, w, l);   // prologue

    #pragma unroll 1
    for (int ci = 0; ci < 4; ++ci) {
        const int cur = ci & 1;
        if (ci < 3) {
            stage(xin, ci + 1, rows[cur ^ 1], halo[cur ^ 1], y0, X0, w, l);
            // wait the OLDEST 7 (= ci's loads); ci+1's 7 stay in flight
            asm volatile("s_waitcnt vmcnt(7)\n\ts_barrier" ::: "memory");
        } else {
            asm volatile("s_waitcnt vmcnt(0)\n\ts_barrier" ::: "memory");
        }
        compute_ci(acc, rows[cur], halo[cur], wt, ci, y0, t, l, xlo, xhi);
        if (ci < 3)
            asm volatile("s_barrier" ::: "memory");  // readers done before
                                                     // next stage overwrites
    }

    const int x0g = X0 + 4 * t;
    #pragma unroll
    for (int o = 0; o < 4; ++o) {
        const long long obase = (long long)(y0 + o) * IW + x0g;
        #pragma unroll
        for (int co = 0; co < 4; ++co) {
            v4f ov;
            ov.x = acc[o][co][0]; ov.y = acc[o][co][1];
            ov.z = acc[o][co][2]; ov.w = acc[o][co][3];
            __builtin_nontemporal_store(ov,
                reinterpret_cast<v4f*>(out + co * HWsz + obase));
        }
    }
}

extern "C" void kernel_launch(void* const* d_in, const int* in_sizes, int n_in,
                              void* d_out, int out_size, void* d_ws, size_t ws_size,
                              hipStream_t stream) {
    const float* xin = (const float*)d_in[0];
    const float* wt  = (const float*)d_in[1];
    float* out       = (float*)d_out;

    dim3 grid(4096), block(256);
    hipLaunchKernelGGL(conv3x3_kernel, grid, block, 0, stream, xin, wt, out);
}

// Round 11
// 103.769 us; speedup vs baseline: 1.0240x; 1.0240x over previous
//
#include <hip/hip_runtime.h>

// Conv2d 3x3, cin=4, cout=4, pad=1, stride=1 on [4,4096,4096] fp32.
//
// Round-11 = round-9 (97.9 us: 2-phase global_load_lds pipeline, counted
// vmcnt(7), XCD swizzle, nt stores) with ONE change: the 8-way-conflicted
// scalar halo reads rbuf[4t-1]/rbuf[4t+4] are replaced by aligned b128
// reads of the NEIGHBOR chunks (rbuf[4(t-1)] -> .w, rbuf[4(t+1)] -> .x),
// the same conflict-free stride-16B pattern as the interior read, with
// clamped indices + cndmask for the t==0 / t==255 strip edges (hbuf) and
// image edges (zero). No shfl (round-10 lesson: ds_bpermute + dependency
// chain cost more than the conflicts it removed).

#define IW 4096
#define IH 4096
constexpr long long HWsz = (long long)IH * IW;

typedef float v4f __attribute__((ext_vector_type(4)));

#define LROW 1024

__device__ __forceinline__ void gload_lds16(const float* g, float* l) {
    __builtin_amdgcn_global_load_lds(
        (const __attribute__((address_space(1))) char*)g,
        (__attribute__((address_space(3))) char*)l, 16, 0, 0);
}
__device__ __forceinline__ void gload_lds4(const float* g, float* l) {
    __builtin_amdgcn_global_load_lds(
        (const __attribute__((address_space(1))) char*)g,
        (__attribute__((address_space(3))) char*)l, 4, 0, 0);
}

// issue 7 DMAs per wave: 6 interior row-chunks (width 16) + 1 halo (width 4)
__device__ __forceinline__ void stage(const float* __restrict__ xin, int ci,
                                      float (*rbuf)[LROW], float* hbuf,
                                      int y0, int X0, int w, int l) {
    const float* plane = xin + (long long)ci * HWsz;
    const int xg = X0 + 256 * w + 4 * l;          // per-lane global x
    #pragma unroll
    for (int r = 0; r < 6; ++r) {
        int yy = y0 - 1 + r;
        int yc = yy < 0 ? 0 : (yy >= IH ? IH - 1 : yy);   // clamp: pad rows
        gload_lds16(plane + (long long)yc * IW + xg, &rbuf[r][256 * w]);
    }
    if (l < 3) {                                   // 4 waves x 3 lanes = 12 slots
        const int s   = 3 * w + l;                 // slot = 2*r + side
        const int r   = s >> 1;
        const int sid = s & 1;
        int yy = y0 - 1 + r;
        int yc = yy < 0 ? 0 : (yy >= IH ? IH - 1 : yy);
        int x  = sid ? (X0 + 1024) : (X0 - 1);
        int xc = x < 0 ? 0 : (x >= IW ? IW - 1 : x);
        gload_lds4(plane + (long long)yc * IW + xc, &hbuf[3 * w]);
    }
}

__device__ __forceinline__ void compute_ci(float acc[4][4][4],
                                           const float (*rbuf)[LROW],
                                           const float* hbuf,
                                           const float* __restrict__ wt, int ci,
                                           int y0, int t, int iL, int iR,
                                           bool xlo, bool xhi) {
    #pragma unroll
    for (int dy = 0; dy < 6; ++dy) {
        const int yy = y0 - 1 + dy;
        if (yy >= 0 && yy < IH) {                  // wave-uniform row skip
            // three independent, aligned, conflict-free b128 reads
            const v4f a  = *reinterpret_cast<const v4f*>(&rbuf[dy][4 * t]);
            const v4f lv = *reinterpret_cast<const v4f*>(&rbuf[dy][iL]);
            const v4f rv = *reinterpret_cast<const v4f*>(&rbuf[dy][iR]);
            // uniform-address broadcast reads (no conflict), then selects
            const float hL = hbuf[2 * dy];
            const float hR = hbuf[2 * dy + 1];
            const float L = (t == 0)   ? (xlo ? 0.f : hL) : lv.w;
            const float R = (t == 255) ? (xhi ? 0.f : hR) : rv.x;
            float vv[6] = {L, a.x, a.y, a.z, a.w, R};
            #pragma unroll
            for (int rk = 0; rk < 3; ++rk) {
                const int o = dy - rk;             // output row offset
                if (o >= 0 && o < 4) {
                    #pragma unroll
                    for (int co = 0; co < 4; ++co) {
                        #pragma unroll
                        for (int kx = 0; kx < 3; ++kx) {
                            const float w = wt[((co * 4 + ci) * 3 + rk) * 3 + kx];
                            #pragma unroll
                            for (int p = 0; p < 4; ++p)
                                acc[o][co][p] = fmaf(w, vv[p + kx], acc[o][co][p]);
                        }
                    }
                }
            }
        }
    }
}

__global__ __launch_bounds__(256) void conv3x3_kernel(
    const float* __restrict__ xin,   // [4][4096][4096]
    const float* __restrict__ wt,    // [4][4][3][3]
    float* __restrict__ out)         // [4][4096][4096]
{
    __shared__ __align__(16) float rows[2][6][LROW];   // 49152 B
    __shared__ float halo[2][12];

    // grid 4096 = 1024 row-blocks x 4 x-strips; bijective XCD swizzle
    const int bid = blockIdx.x;
    const int swz = (bid & 7) * 512 + (bid >> 3);
    const int rowblk = swz >> 2;
    const int xq     = swz & 3;
    const int y0     = rowblk << 2;               // 4 output rows
    const int X0     = xq << 10;                  // 1024-px strip
    const int t      = (int)threadIdx.x;
    const int w      = t >> 6, l = t & 63;
    const bool xlo   = (X0 == 0);
    const bool xhi   = (X0 + 1024 == IW);
    // clamped neighbor-chunk indices (in-range garbage, selected out)
    const int iL = 4 * (t == 0 ? 0 : t - 1);
    const int iR = 4 * (t == 255 ? 255 : t + 1);

    float acc[4][4][4];
    #pragma unroll
    for (int o = 0; o < 4; ++o)
        #pragma unroll
        for (int co = 0; co < 4; ++co)
            #pragma unroll
            for (int p = 0; p < 4; ++p) acc[o][co][p] = 0.f;

    stage(xin, 0, rows[0], halo[0], y0, X0, w, l);   // prologue

    #pragma unroll 1
    for (int ci = 0; ci < 4; ++ci) {
        const int cur = ci & 1;
        if (ci < 3) {
            stage(xin, ci + 1, rows[cur ^ 1], halo[cur ^ 1], y0, X0, w, l);
            // wait the OLDEST 7 (= ci's loads); ci+1's 7 stay in flight
            asm volatile("s_waitcnt vmcnt(7)\n\ts_barrier" ::: "memory");
        } else {
            asm volatile("s_waitcnt vmcnt(0)\n\ts_barrier" ::: "memory");
        }
        compute_ci(acc, rows[cur], halo[cur], wt, ci, y0, t, iL, iR, xlo, xhi);
        if (ci < 3)
            asm volatile("s_barrier" ::: "memory");  // readers done before
                                                     // next stage overwrites
    }

    const int x0g = X0 + 4 * t;
    #pragma unroll
    for (int o = 0; o < 4; ++o) {
        const long long obase = (long long)(y0 + o) * IW + x0g;
        #pragma unroll
        for (int co = 0; co < 4; ++co) {
            v4f ov;
            ov.x = acc[o][co][0]; ov.y = acc[o][co][1];
            ov.z = acc[o][co][2]; ov.w = acc[o][co][3];
            __builtin_nontemporal_store(ov,
                reinterpret_cast<v4f*>(out + co * HWsz + obase));
        }
    }
}

extern "C" void kernel_launch(void* const* d_in, const int* in_sizes, int n_in,
                              void* d_out, int out_size, void* d_ws, size_t ws_size,
                              hipStream_t stream) {
    const float* xin = (const float*)d_in[0];
    const float* wt  = (const float*)d_in[1];
    float* out       = (float*)d_out;

    dim3 grid(4096), block(256);
    hipLaunchKernelGGL(conv3x3_kernel, grid, block, 0, stream, xin, wt, out);
}